// Round 1
// baseline (338.309 us; speedup 1.0000x reference)
//
#include <hip/hip_runtime.h>
#include <math.h>

// Problem: AttentionPool  B=32, N=8192, D=256 (all f32; mask bool->int32)
// out[b,d] = sum_n softmax_n(mask ? x[b]·q : -inf) * x[b,n,d]

#define BB 32
#define NN 8192
#define DD 256
#define CHUNKS 32                      // chunks per batch row
#define ROWS_PER_CHUNK (NN / CHUNKS)   // 256 rows
#define ROWS_PER_WAVE 64

__global__ __launch_bounds__(256) void pool_partial(
    const float* __restrict__ x,     // [B][N][D]
    const int*   __restrict__ mask,  // [B][N]
    const float* __restrict__ q,     // [D]
    float* __restrict__ acc_part,    // [B][CHUNKS][D]
    float* __restrict__ m_part,      // [B][CHUNKS]
    float* __restrict__ s_part)      // [B][CHUNKS]
{
    const int b     = blockIdx.x / CHUNKS;
    const int chunk = blockIdx.x % CHUNKS;
    const int wave  = threadIdx.x >> 6;
    const int lane  = threadIdx.x & 63;

    const int row0 = chunk * ROWS_PER_CHUNK + wave * ROWS_PER_WAVE;

    // each lane owns 4 columns: d = lane*4 .. lane*4+3
    const float4 qv = reinterpret_cast<const float4*>(q)[lane];

    // one mask value per lane -> 64-bit active-row mask for this wave
    const int mv = mask[(size_t)b * NN + row0 + lane];
    unsigned long long act = __ballot(mv != 0);

    float  m = -INFINITY, s = 0.0f;
    float4 acc = make_float4(0.f, 0.f, 0.f, 0.f);

    const float4* xb = reinterpret_cast<const float4*>(x + (size_t)b * NN * DD);

    while (act) {
        const int j = __ffsll((long long)act) - 1;
        act &= act - 1;
        const int row = row0 + j;

        // whole wave loads one 1KiB row: lane i -> 16B at d=lane*4
        const float4 xv = xb[(size_t)row * (DD / 4) + lane];

        // dot(x_row, q): lane-partial then 64-lane butterfly reduce
        float part = xv.x * qv.x + xv.y * qv.y + xv.z * qv.z + xv.w * qv.w;
        #pragma unroll
        for (int off = 32; off > 0; off >>= 1)
            part += __shfl_xor(part, off, 64);
        const float logit = part;   // wave-uniform

        if (logit > m) {            // wave-uniform branch
            const float sc = __expf(m - logit);   // exp(-inf)=0 on first hit
            s = s * sc + 1.0f;                    // p_new = exp(0) = 1
            acc.x = acc.x * sc + xv.x;
            acc.y = acc.y * sc + xv.y;
            acc.z = acc.z * sc + xv.z;
            acc.w = acc.w * sc + xv.w;
            m = logit;
        } else {
            const float p = __expf(logit - m);
            s += p;
            acc.x += p * xv.x;
            acc.y += p * xv.y;
            acc.z += p * xv.z;
            acc.w += p * xv.w;
        }
    }

    // ---- combine 4 waves in LDS ----
    __shared__ float lacc[4][DD];
    __shared__ float lm[4], ls[4];
    reinterpret_cast<float4*>(lacc[wave])[lane] = acc;
    if (lane == 0) { lm[wave] = m; ls[wave] = s; }
    __syncthreads();

    const int t = threadIdx.x;      // column index 0..255
    const float mstar = fmaxf(fmaxf(lm[0], lm[1]), fmaxf(lm[2], lm[3]));
    float stot = 0.f, a = 0.f;
    #pragma unroll
    for (int w = 0; w < 4; ++w) {
        const float wgt = (ls[w] > 0.f) ? __expf(lm[w] - mstar) : 0.f;
        stot += wgt * ls[w];
        a    += wgt * lacc[w][t];
    }
    const int pi = b * CHUNKS + chunk;
    acc_part[(size_t)pi * DD + t] = a;
    if (t == 0) { m_part[pi] = mstar; s_part[pi] = stot; }
}

__global__ __launch_bounds__(256) void pool_final(
    const float* __restrict__ acc_part,
    const float* __restrict__ m_part,
    const float* __restrict__ s_part,
    float* __restrict__ out)          // [B][D]
{
    const int b = blockIdx.x;
    const int t = threadIdx.x;

    __shared__ float sm[CHUNKS], ss[CHUNKS];
    if (t < CHUNKS) {
        sm[t] = m_part[b * CHUNKS + t];
        ss[t] = s_part[b * CHUNKS + t];
    }
    __syncthreads();

    float M = -INFINITY;
    #pragma unroll
    for (int c = 0; c < CHUNKS; ++c)
        if (ss[c] > 0.f) M = fmaxf(M, sm[c]);

    float S = 0.f, a = 0.f;
    #pragma unroll
    for (int c = 0; c < CHUNKS; ++c) {
        const float wgt = (ss[c] > 0.f) ? __expf(sm[c] - M) : 0.f;
        S += wgt * ss[c];
        a += wgt * acc_part[((size_t)b * CHUNKS + c) * DD + t];
    }
    out[b * DD + t] = a / S;
}

extern "C" void kernel_launch(void* const* d_in, const int* in_sizes, int n_in,
                              void* d_out, int out_size, void* d_ws, size_t ws_size,
                              hipStream_t stream) {
    const float* x    = (const float*)d_in[0];
    const int*   mask = (const int*)  d_in[1];
    const float* q    = (const float*)d_in[2];
    float* out = (float*)d_out;

    float* acc_part = (float*)d_ws;                       // [B][CHUNKS][D]
    float* m_part   = acc_part + (size_t)BB * CHUNKS * DD; // [B][CHUNKS]
    float* s_part   = m_part + (size_t)BB * CHUNKS;        // [B][CHUNKS]

    pool_partial<<<BB * CHUNKS, 256, 0, stream>>>(x, mask, q, acc_part, m_part, s_part);
    pool_final<<<BB, 256, 0, stream>>>(acc_part, m_part, s_part, out);
}

// Round 2
// 337.253 us; speedup vs baseline: 1.0031x; 1.0031x over previous
//
#include <hip/hip_runtime.h>
#include <math.h>

// AttentionPool: B=32, N=8192, D=256 (f32; mask int32)
// out[b,d] = sum_n softmax_n(mask ? x[b]·q : -inf) * x[b,n,d]
//
// pool_partial: 1024 blocks (32 b × 32 chunks), 4 waves/block, 64 rows/wave.
//   Wave layout: quarter g = lane>>4 owns rows ≡ g (mod 4); lane covers
//   columns (lane&15)*16..+15 (4×float4 = 64B = full cache line per lane).
//   Per-quarter branchless online softmax; 4-shuffle reduce per 4 rows;
//   1-deep register prefetch of the next active row; masked rows skipped
//   (no load issued).
// pool_final: combine 32 chunk-partials per batch row.

#define BB 32
#define NN 8192
#define DD 256
#define CHUNKS 32
#define RPC (NN / CHUNKS)   // 256 rows per chunk

__device__ __forceinline__ float dot4(float4 a, float4 b) {
    return fmaf(a.x, b.x, fmaf(a.y, b.y, fmaf(a.z, b.z, a.w * b.w)));
}

#define UPD(A, C)                       \
    A.x = fmaf(A.x, sc, w * C.x);       \
    A.y = fmaf(A.y, sc, w * C.y);       \
    A.z = fmaf(A.z, sc, w * C.z);       \
    A.w = fmaf(A.w, sc, w * C.w);

__global__ __launch_bounds__(256) void pool_partial(
    const float* __restrict__ x,     // [B][N][D]
    const int*   __restrict__ mask,  // [B][N]
    const float* __restrict__ q,     // [D]
    float* __restrict__ acc_part,    // [B][CHUNKS][D]
    float* __restrict__ m_part,      // [B][CHUNKS]
    float* __restrict__ s_part)      // [B][CHUNKS]
{
    const int b     = blockIdx.x / CHUNKS;
    const int chunk = blockIdx.x % CHUNKS;
    const int wave  = threadIdx.x >> 6;
    const int lane  = threadIdx.x & 63;
    const int g     = lane >> 4;   // quarter: owns rows ≡ g (mod 4)
    const int c     = lane & 15;   // column group: cols c*16 .. c*16+15

    const int row0 = chunk * RPC + wave * 64;

    const float4* q4 = reinterpret_cast<const float4*>(q) + c * 4;
    const float4 q0 = q4[0], q1 = q4[1], q2 = q4[2], q3 = q4[3];

    const int mv = mask[(size_t)b * NN + row0 + lane];
    const unsigned long long wmask = __ballot(mv != 0);
    unsigned long long qm = wmask & (0x1111111111111111ULL << g);

    float m = -INFINITY, s = 0.0f;
    float4 a0 = make_float4(0.f, 0.f, 0.f, 0.f), a1 = a0, a2 = a0, a3 = a0;

    const float4* xb = reinterpret_cast<const float4*>(x + (size_t)b * NN * DD);

    if (qm) {
        int j = __ffsll(qm) - 1; qm &= qm - 1;
        const float4* rp = xb + (size_t)(row0 + j) * (DD / 4) + c * 4;
        float4 c0 = rp[0], c1 = rp[1], c2 = rp[2], c3 = rp[3];
        for (;;) {
            const bool more = (qm != 0ULL);
            float4 n0 = a0, n1 = a0, n2 = a0, n3 = a0;
            if (more) {
                const int jn = __ffsll(qm) - 1; qm &= qm - 1;
                const float4* np = xb + (size_t)(row0 + jn) * (DD / 4) + c * 4;
                n0 = np[0]; n1 = np[1]; n2 = np[2]; n3 = np[3];
            }
            // full 256-wide dot of this quarter's row (16 lanes × 16 cols)
            float p = dot4(c0, q0) + dot4(c1, q1) + dot4(c2, q2) + dot4(c3, q3);
            p += __shfl_xor(p, 1, 16);
            p += __shfl_xor(p, 2, 16);
            p += __shfl_xor(p, 4, 16);
            p += __shfl_xor(p, 8, 16);
            // branchless online-softmax update (quarter-uniform)
            const float mnew = fmaxf(m, p);
            const float sc = __expf(m - mnew);   // exp(-inf)=0 on first row
            const float w  = __expf(p - mnew);
            s = fmaf(s, sc, w);
            UPD(a0, c0); UPD(a1, c1); UPD(a2, c2); UPD(a3, c3);
            m = mnew;
            if (!more) break;
            c0 = n0; c1 = n1; c2 = n2; c3 = n3;
        }
    }

    // ---- combine 16 states (4 waves × 4 quarters) in LDS ----
    __shared__ float lacc[16][DD];   // 16 KB
    __shared__ float lm[16], ls[16];
    const int sid = wave * 4 + g;
    float4* dst = reinterpret_cast<float4*>(&lacc[sid][c * 16]);
    dst[0] = a0; dst[1] = a1; dst[2] = a2; dst[3] = a3;
    if (c == 0) { lm[sid] = m; ls[sid] = s; }
    __syncthreads();

    const int t = threadIdx.x;   // column 0..255
    float M = -INFINITY;
    #pragma unroll
    for (int i = 0; i < 16; ++i)
        if (ls[i] > 0.f) M = fmaxf(M, lm[i]);
    float S = 0.f, A = 0.f;
    #pragma unroll
    for (int i = 0; i < 16; ++i) {
        const float wgt = (ls[i] > 0.f) ? __expf(lm[i] - M) : 0.f;
        S += wgt * ls[i];
        A += wgt * lacc[i][t];
    }
    const int pi = b * CHUNKS + chunk;
    acc_part[(size_t)pi * DD + t] = A;
    if (t == 0) { m_part[pi] = M; s_part[pi] = S; }
}

__global__ __launch_bounds__(256) void pool_final(
    const float* __restrict__ acc_part,
    const float* __restrict__ m_part,
    const float* __restrict__ s_part,
    float* __restrict__ out)          // [B][D]
{
    const int b = blockIdx.x;
    const int t = threadIdx.x;

    __shared__ float sm[CHUNKS], ss[CHUNKS];
    if (t < CHUNKS) {
        sm[t] = m_part[b * CHUNKS + t];
        ss[t] = s_part[b * CHUNKS + t];
    }
    __syncthreads();

    float M = -INFINITY;
    #pragma unroll
    for (int c = 0; c < CHUNKS; ++c)
        if (ss[c] > 0.f) M = fmaxf(M, sm[c]);

    float S = 0.f, a = 0.f;
    #pragma unroll
    for (int c = 0; c < CHUNKS; ++c) {
        const float wgt = (ss[c] > 0.f) ? __expf(sm[c] - M) : 0.f;
        S += wgt * ss[c];
        a += wgt * acc_part[((size_t)b * CHUNKS + c) * DD + t];
    }
    out[b * DD + t] = a / S;
}

extern "C" void kernel_launch(void* const* d_in, const int* in_sizes, int n_in,
                              void* d_out, int out_size, void* d_ws, size_t ws_size,
                              hipStream_t stream) {
    const float* x    = (const float*)d_in[0];
    const int*   mask = (const int*)  d_in[1];
    const float* q    = (const float*)d_in[2];
    float* out = (float*)d_out;

    float* acc_part = (float*)d_ws;                        // [B][CHUNKS][D]
    float* m_part   = acc_part + (size_t)BB * CHUNKS * DD; // [B][CHUNKS]
    float* s_part   = m_part + (size_t)BB * CHUNKS;        // [B][CHUNKS]

    pool_partial<<<BB * CHUNKS, 256, 0, stream>>>(x, mask, q, acc_part, m_part, s_part);
    pool_final<<<BB, 256, 0, stream>>>(acc_part, m_part, s_part, out);
}